// Round 5
// baseline (1074.320 us; speedup 1.0000x reference)
//
#include <hip/hip_runtime.h>
#include <math.h>

// Problem constants
#define NTOK 8192
#define MDIM 4096
#define NEXP 64
#define DV   (MDIM / 4)   // float4 per x/W row = 1024
#define CAPACITY 128.0f

// Output layout (all fp32): [indices 8192][capacity 1][locations 8192][gates 8192][num_experts 1]
#define OFF_IDX  0
#define OFF_CAP  8192
#define OFF_LOC  8193
#define OFF_GATE 16385
#define OFF_NE   24577

// ws layout in 4-byte units: [cnt 8192][rk 8192][done 16][partials S*8192*64]
#define WS_CNT_OFF  0
#define WS_RK_OFF   8192
#define WS_DONE_OFF 16384
#define WS_PART_OFF 16400

// ---------------------------------------------------------------------------
// Gate partial GEMM, R5 structure ("register-resident x, no LDS"):
//  - lane = (token, expert-quarter): trel = lane>>2 (16 tok/wave), q = lane&3
//    (16 experts/lane). block 256 = 64 tokens; grid = (128, S) -> 4096 waves
//    at S=8 (16 waves/CU) with unchanged 16 MB partials.
//  - x: per-lane global->VGPR stream, each element reused 16x from register.
//    (R4 died on LDS broadcast reads: 8.4M ds_read_b128 ~= 137 us of LDS
//    pipe; x never touches LDS now. No barriers at all.)
//  - W: per-lane vector loads, 4 KB/chunk working set, L1-hot, shared by all
//    resident waves. 16 loads per 256 fma.
//  - acc[16]: k ascending within slice; reduce sums slices ascending ->
//    deterministic.
// ---------------------------------------------------------------------------
template<int S>
__global__ __launch_bounds__(256, 3) void gate_partial(
    const float* __restrict__ x,
    const float* __restrict__ W,
    float* __restrict__ part,
    int* __restrict__ done)
{
    constexpr int KS = MDIM / S;   // K per slice (512 at S=8)
    constexpr int NC = KS / 16;    // 16-K chunks per slice

    const int tid  = threadIdx.x;
    const int lane = tid & 63;
    const int wv   = tid >> 6;
    const int trel = lane >> 2;    // token within wave
    const int q    = lane & 3;     // expert quarter
    const int tok  = blockIdx.x * 64 + wv * 16 + trel;
    const int k0   = blockIdx.y * KS;

    // zero the tail kernel's ticket counter (ws is poisoned 0xAA each launch;
    // kernel-boundary ordering makes this visible to reduce_all)
    if (blockIdx.x == 0 && blockIdx.y == 0 && tid == 0) *done = 0;

    const float4* __restrict__ x4 = (const float4*)x + (size_t)tok * DV + (k0 >> 2);
    const float4* __restrict__ Wq = (const float4*)W + (size_t)(q * 16) * DV + (k0 >> 2);

    float acc[16];
    #pragma unroll
    for (int i = 0; i < 16; ++i) acc[i] = 0.f;

    float4 xc[4], xn[4];
    #pragma unroll
    for (int r = 0; r < 4; ++r) xc[r] = x4[r];

    for (int c = 0; c < NC; ++c) {
        if (c + 1 < NC) {
            #pragma unroll
            for (int r = 0; r < 4; ++r) xn[r] = x4[(c + 1) * 4 + r];
        }
        #pragma unroll
        for (int eg = 0; eg < 4; ++eg) {
            float4 w[4][4];
            #pragma unroll
            for (int e = 0; e < 4; ++e) {
                const float4* we = Wq + (size_t)(eg * 4 + e) * DV + c * 4;
                #pragma unroll
                for (int r = 0; r < 4; ++r) w[e][r] = we[r];
            }
            #pragma unroll
            for (int r = 0; r < 4; ++r) {
                // k = c*16 + r*4 + comp, ascending per acc; dep distance 4
                #pragma unroll
                for (int e = 0; e < 4; ++e) acc[eg*4+e] = fmaf(xc[r].x, w[e][r].x, acc[eg*4+e]);
                #pragma unroll
                for (int e = 0; e < 4; ++e) acc[eg*4+e] = fmaf(xc[r].y, w[e][r].y, acc[eg*4+e]);
                #pragma unroll
                for (int e = 0; e < 4; ++e) acc[eg*4+e] = fmaf(xc[r].z, w[e][r].z, acc[eg*4+e]);
                #pragma unroll
                for (int e = 0; e < 4; ++e) acc[eg*4+e] = fmaf(xc[r].w, w[e][r].w, acc[eg*4+e]);
            }
        }
        if (c + 1 < NC) {
            #pragma unroll
            for (int r = 0; r < 4; ++r) xc[r] = xn[r];
        }
    }

    // lane (trel,q) owns experts q*16..q*16+15 of its token: contiguous 64 B;
    // wave covers a contiguous 4 KB block (lane = trel*4+q order)
    float4* pp = (float4*)(part + (((size_t)blockIdx.y * NTOK + tok) * 64 + q * 16));
    pp[0] = make_float4(acc[0],  acc[1],  acc[2],  acc[3]);
    pp[1] = make_float4(acc[4],  acc[5],  acc[6],  acc[7]);
    pp[2] = make_float4(acc[8],  acc[9],  acc[10], acc[11]);
    pp[3] = make_float4(acc[12], acc[13], acc[14], acc[15]);
}

// ---------------------------------------------------------------------------
// Fused tail: reduce partials + argmax/softmax + histogram/rank, then the
// LAST block (device-scope int ticket, deterministic) does the per-expert
// scan over all 128 chunks and writes locations. One dispatch total.
// ---------------------------------------------------------------------------
template<int S>
__global__ __launch_bounds__(256) void reduce_all(
    const float* __restrict__ part,
    float* __restrict__ out,
    int* __restrict__ cnt,
    int* __restrict__ rk,
    int* __restrict__ done)
{
    __shared__ int eidx[64];
    __shared__ int lcnt[128 * 64];   // 32 KB, used by the winning block
    __shared__ int wtot[4 * 64];
    __shared__ int tick_s;

    const int tid  = threadIdx.x;
    const int lane = tid & 63;
    const int wv   = tid >> 6;
    const int tok0 = blockIdx.x * 64;
    const int trel = wv * 16 + (lane >> 2);
    const int tok  = tok0 + trel;
    const int q    = lane & 3;

    const float4* __restrict__ p4 = (const float4*)part;

    // ---- phase 1: deterministic slice-ascending reduce, 16 experts/lane
    float4 a[4];
    #pragma unroll
    for (int r = 0; r < 4; ++r) a[r] = make_float4(0.f, 0.f, 0.f, 0.f);
    for (int s = 0; s < S; ++s) {
        #pragma unroll
        for (int r = 0; r < 4; ++r) {
            float4 v = p4[((size_t)s * NTOK + tok) * 16 + q * 4 + r];
            a[r].x += v.x; a[r].y += v.y; a[r].z += v.z; a[r].w += v.w;
        }
    }

    float vals[16];
    #pragma unroll
    for (int r = 0; r < 4; ++r) {
        vals[r * 4 + 0] = a[r].x; vals[r * 4 + 1] = a[r].y;
        vals[r * 4 + 2] = a[r].z; vals[r * 4 + 3] = a[r].w;
    }

    float bm = vals[0];
    int   be = q * 16;
    #pragma unroll
    for (int j = 1; j < 16; ++j)
        if (vals[j] > bm) { bm = vals[j]; be = q * 16 + j; }
    #pragma unroll
    for (int off = 1; off <= 2; off <<= 1) {
        float om = __shfl_xor(bm, off, 64);
        int   oe = __shfl_xor(be, off, 64);
        if (om > bm || (om == bm && oe < be)) { bm = om; be = oe; }
    }

    float es = 0.f;
    #pragma unroll
    for (int j = 0; j < 16; ++j) es += expf(vals[j] - bm);
    #pragma unroll
    for (int off = 1; off <= 2; off <<= 1)
        es += __shfl_xor(es, off, 64);

    if (q == 0) {
        out[OFF_IDX  + tok] = (float)be;
        out[OFF_GATE + tok] = 1.0f / es;
        eidx[trel] = be;
    }
    __syncthreads();

    // ---- phase 2: per-chunk histogram + in-chunk ranks (wave 0)
    if (tid < 64) {
        const int e = eidx[tid];
        const unsigned long long lt =
            (tid == 0) ? 0ull : ((~0ull) >> (64 - tid));
        unsigned long long mymask = 0;
        int myrk = 0;
        for (int ee = 0; ee < 64; ++ee) {
            unsigned long long mb = __ballot(e == ee);
            if (tid == ee) mymask = mb;
            if (e == ee)   myrk   = (int)__popcll(mb & lt);
        }
        cnt[blockIdx.x * 64 + tid] = (int)__popcll(mymask);
        rk[tok0 + tid] = myrk;
    }
    if (tid == 0 && blockIdx.x == 0) {
        out[OFF_CAP] = CAPACITY;
        out[OFF_NE]  = (float)NEXP;
    }

    // ---- phase 3: last block scans + finalizes locations
    __threadfence();                      // release cnt/rk/idx (agent scope)
    __syncthreads();
    if (tid == 0) tick_s = atomicAdd(done, 1);
    __syncthreads();
    if (tick_s == 127) {                  // block-uniform -> syncthreads legal
        __threadfence();                  // acquire: invalidate stale caches

        for (int j = 0; j < 32; ++j)
            lcnt[j * 256 + tid] = cnt[j * 256 + tid];
        __syncthreads();

        // wave wv: chunks wv*32..wv*32+31, lane = expert
        int sum = 0;
        for (int j = 0; j < 32; ++j) sum += lcnt[(wv * 32 + j) * 64 + lane];
        wtot[wv * 64 + lane] = sum;
        __syncthreads();

        if (tid < 64) {
            int run = 0;
            #pragma unroll
            for (int w2 = 0; w2 < 4; ++w2) {
                int t = wtot[w2 * 64 + tid];
                wtot[w2 * 64 + tid] = run;
                run += t;
            }
        }
        __syncthreads();

        int run = wtot[wv * 64 + lane];
        for (int j = 0; j < 32; ++j) {
            int c = (wv * 32 + j) * 64 + lane;
            int v = lcnt[c];
            lcnt[c] = run;
            run += v;
        }
        __syncthreads();

        for (int j = 0; j < 32; ++j) {
            int s = j * 256 + tid;
            int e = (int)out[OFF_IDX + s];
            out[OFF_LOC + s] = (float)(lcnt[(s >> 6) * 64 + e] + rk[s]);
        }
    }
}

extern "C" void kernel_launch(void* const* d_in, const int* in_sizes, int n_in,
                              void* d_out, int out_size, void* d_ws, size_t ws_size,
                              hipStream_t stream)
{
    const float* x = (const float*)d_in[0];   // [8192, 4096] fp32
    const float* W = (const float*)d_in[1];   // [64, 4096] fp32
    float* out = (float*)d_out;               // 24578 fp32

    int*   cnt  = (int*)d_ws + WS_CNT_OFF;
    int*   rk   = (int*)d_ws + WS_RK_OFF;
    int*   done = (int*)d_ws + WS_DONE_OFF;
    float* part = (float*)d_ws + WS_PART_OFF;

    const size_t base = (size_t)WS_PART_OFF * 4;
    const size_t per_slice = (size_t)NTOK * 64 * 4;   // 2 MB

    if (ws_size >= base + 8 * per_slice) {            // known to fit (R4 ran S=8)
        gate_partial<8><<<dim3(128, 8), 256, 0, stream>>>(x, W, part, done);
        reduce_all<8><<<128, 256, 0, stream>>>(part, out, cnt, rk, done);
    } else {
        gate_partial<4><<<dim3(128, 4), 256, 0, stream>>>(x, W, part, done);
        reduce_all<4><<<128, 256, 0, stream>>>(part, out, cnt, rk, done);
    }
}

// Round 6
// 490.331 us; speedup vs baseline: 2.1910x; 2.1910x over previous
//
#include <hip/hip_runtime.h>
#include <math.h>

// Problem constants
#define NTOK 8192
#define MDIM 4096
#define NEXP 64
#define DV   (MDIM / 4)   // float4 per x/W row = 1024
#define CAPACITY 128.0f
#define SPLIT 4           // K slices (4 x 1024)

// Output layout (all fp32): [indices 8192][capacity 1][locations 8192][gates 8192][num_experts 1]
#define OFF_IDX  0
#define OFF_CAP  8192
#define OFF_LOC  8193
#define OFF_GATE 16385
#define OFF_NE   24577

// ws layout in 4-byte units:
// [done 16][Wp 64*1024*4 = 262144][cnt 8192][rk 8192][partials SPLIT*8192*64]
#define WS_DONE_OFF 0
#define WS_WP_OFF   16
#define WS_CNT_OFF  (16 + 262144)
#define WS_RK_OFF   (16 + 262144 + 8192)
#define WS_PART_OFF (16 + 262144 + 16384)

// ---------------------------------------------------------------------------
// W pre-pack: Wp[k4][e] = float4(W[e][4*k4 .. 4*k4+3]). Makes the gate's
// per-lane (lane = expert) W read a fully COALESCED b128 (consecutive lanes
// 16 B apart) instead of 64 scattered 16 KB-strided lines (R5's killer).
// Reads coalesced per expert row; scattered writes are only 1 MB.
// ---------------------------------------------------------------------------
__global__ __launch_bounds__(256) void wp_pack(
    const float* __restrict__ W, float* __restrict__ Wp)
{
    const float4* __restrict__ W4  = (const float4*)W;
    float4* __restrict__       Wp4 = (float4*)Wp;
    int i  = blockIdx.x * 256 + threadIdx.x;   // 0..65535
    int e  = i >> 10;
    int k4 = i & 1023;
    Wp4[k4 * 64 + e] = W4[e * 1024 + k4];
}

// ---------------------------------------------------------------------------
// Gate partial GEMM, R6 ("scalar-pipe x, zero LDS"):
//  - lane = expert (64). Wave = 8 tokens. Block = 4 waves = 32 tokens.
//    grid = (256 groups, SPLIT slices) -> 4096 waves = 16/CU.
//  - x: wave-UNIFORM addresses, all loads precede all stores -> SMEM
//    s_load_dwordx16 into SGPRs (scalar pipe: parallel to VALU, no LDS, no
//    VMEM). Double-buffered 32-float sets, prefetch 1 token ahead; latency
//    covered by 16 waves/CU TLP.
//  - W: from Wp (packed [k4][e]) -> per-lane b128, fully coalesced, 8 regs
//    per 32-K chunk reused across the 8 tokens.
//  - acc: 2 interleaved FMA chains per token (dep distance = 4 cyc = v_fma
//    latency). K ascending within slice; reduce sums slices ascending ->
//    deterministic, same order as the R5 pass.
//  - VGPR ~ 60 (w 32 + acc 16 + addr) -> no spill at (256,4); LDS = 0.
// ---------------------------------------------------------------------------
template<int S>
__global__ __launch_bounds__(256, 4) void gate_partial(
    const float* __restrict__ x,
    const float* __restrict__ Wp,
    float* __restrict__ part,
    int* __restrict__ done)
{
    constexpr int KS = MDIM / S;   // 1024 at S=4
    constexpr int NC = KS / 32;    // 32 chunks of 32 K

    const int tid   = threadIdx.x;
    const int lane  = tid & 63;
    const int wv    = __builtin_amdgcn_readfirstlane(tid >> 6);
    const int tok0  = blockIdx.x * 32 + wv * 8;     // wave's 8 tokens
    const int slice = blockIdx.y;
    const int k0    = slice * KS;

    if (blockIdx.x == 0 && slice == 0 && tid == 0) *done = 0;

    const float4* __restrict__ Wp4 = (const float4*)Wp;

    float accA[8], accB[8];
    #pragma unroll
    for (int t = 0; t < 8; ++t) { accA[t] = 0.f; accB[t] = 0.f; }

    // double-buffered uniform x sets (intended home: SGPRs via s_load_dwordx16)
    float xs[2][32];

    // preload (c=0, t=0)
    {
        const float* __restrict__ xr = x + (size_t)tok0 * MDIM + k0;
        #pragma unroll
        for (int i = 0; i < 32; ++i) xs[0][i] = xr[i];
    }

    for (int c = 0; c < NC; ++c) {
        // W chunk: 8 coalesced b128, reused by all 8 tokens
        float4 w[8];
        #pragma unroll
        for (int j = 0; j < 8; ++j)
            w[j] = Wp4[(size_t)((k0 >> 2) + c * 8 + j) * 64 + lane];

        #pragma unroll
        for (int t = 0; t < 8; ++t) {
            const int p = t & 1;
            // prefetch next (c,t) unit's x while computing this one
            const int u = c * 8 + t;
            if (u + 1 < NC * 8) {
                const int c2 = (u + 1) >> 3;
                const int t2 = (u + 1) & 7;
                const float* __restrict__ xn =
                    x + (size_t)(tok0 + t2) * MDIM + k0 + c2 * 32;
                #pragma unroll
                for (int i = 0; i < 32; ++i) xs[p ^ 1][i] = xn[i];
            }
            // 32 FMAs, two interleaved chains (even/odd j)
            float a = accA[t], b = accB[t];
            #pragma unroll
            for (int j = 0; j < 8; j += 2) {
                a = fmaf(xs[p][j * 4 + 0], w[j].x, a);
                b = fmaf(xs[p][j * 4 + 4], w[j + 1].x, b);
                a = fmaf(xs[p][j * 4 + 1], w[j].y, a);
                b = fmaf(xs[p][j * 4 + 5], w[j + 1].y, b);
                a = fmaf(xs[p][j * 4 + 2], w[j].z, a);
                b = fmaf(xs[p][j * 4 + 6], w[j + 1].z, b);
                a = fmaf(xs[p][j * 4 + 3], w[j].w, a);
                b = fmaf(xs[p][j * 4 + 7], w[j + 1].w, b);
            }
            accA[t] = a; accB[t] = b;
        }
    }

    #pragma unroll
    for (int t = 0; t < 8; ++t)
        part[((size_t)slice * NTOK + tok0 + t) * 64 + lane] = accA[t] + accB[t];
}

// ---------------------------------------------------------------------------
// Fused tail (unchanged from the R5 PASS): reduce partials + argmax/softmax +
// histogram/rank; last block (device-scope ticket) scans and writes locations.
// ---------------------------------------------------------------------------
template<int S>
__global__ __launch_bounds__(256) void reduce_all(
    const float* __restrict__ part,
    float* __restrict__ out,
    int* __restrict__ cnt,
    int* __restrict__ rk,
    int* __restrict__ done)
{
    __shared__ int eidx[64];
    __shared__ int lcnt[128 * 64];   // 32 KB, used by the winning block
    __shared__ int wtot[4 * 64];
    __shared__ int tick_s;

    const int tid  = threadIdx.x;
    const int lane = tid & 63;
    const int wv   = tid >> 6;
    const int tok0 = blockIdx.x * 64;
    const int trel = wv * 16 + (lane >> 2);
    const int tok  = tok0 + trel;
    const int q    = lane & 3;

    const float4* __restrict__ p4 = (const float4*)part;

    // phase 1: deterministic slice-ascending reduce, 16 experts/lane
    float4 a[4];
    #pragma unroll
    for (int r = 0; r < 4; ++r) a[r] = make_float4(0.f, 0.f, 0.f, 0.f);
    for (int s = 0; s < S; ++s) {
        #pragma unroll
        for (int r = 0; r < 4; ++r) {
            float4 v = p4[((size_t)s * NTOK + tok) * 16 + q * 4 + r];
            a[r].x += v.x; a[r].y += v.y; a[r].z += v.z; a[r].w += v.w;
        }
    }

    float vals[16];
    #pragma unroll
    for (int r = 0; r < 4; ++r) {
        vals[r * 4 + 0] = a[r].x; vals[r * 4 + 1] = a[r].y;
        vals[r * 4 + 2] = a[r].z; vals[r * 4 + 3] = a[r].w;
    }

    float bm = vals[0];
    int   be = q * 16;
    #pragma unroll
    for (int j = 1; j < 16; ++j)
        if (vals[j] > bm) { bm = vals[j]; be = q * 16 + j; }
    #pragma unroll
    for (int off = 1; off <= 2; off <<= 1) {
        float om = __shfl_xor(bm, off, 64);
        int   oe = __shfl_xor(be, off, 64);
        if (om > bm || (om == bm && oe < be)) { bm = om; be = oe; }
    }

    float es = 0.f;
    #pragma unroll
    for (int j = 0; j < 16; ++j) es += expf(vals[j] - bm);
    #pragma unroll
    for (int off = 1; off <= 2; off <<= 1)
        es += __shfl_xor(es, off, 64);

    if (q == 0) {
        out[OFF_IDX  + tok] = (float)be;
        out[OFF_GATE + tok] = 1.0f / es;
        eidx[trel] = be;
    }
    __syncthreads();

    // phase 2: per-chunk histogram + in-chunk ranks (wave 0)
    if (tid < 64) {
        const int e = eidx[tid];
        const unsigned long long lt =
            (tid == 0) ? 0ull : ((~0ull) >> (64 - tid));
        unsigned long long mymask = 0;
        int myrk = 0;
        for (int ee = 0; ee < 64; ++ee) {
            unsigned long long mb = __ballot(e == ee);
            if (tid == ee) mymask = mb;
            if (e == ee)   myrk   = (int)__popcll(mb & lt);
        }
        cnt[blockIdx.x * 64 + tid] = (int)__popcll(mymask);
        rk[tok0 + tid] = myrk;
    }
    if (tid == 0 && blockIdx.x == 0) {
        out[OFF_CAP] = CAPACITY;
        out[OFF_NE]  = (float)NEXP;
    }

    // phase 3: last block scans + finalizes locations
    __threadfence();
    __syncthreads();
    if (tid == 0) tick_s = atomicAdd(done, 1);
    __syncthreads();
    if (tick_s == 127) {
        __threadfence();

        for (int j = 0; j < 32; ++j)
            lcnt[j * 256 + tid] = cnt[j * 256 + tid];
        __syncthreads();

        int sum = 0;
        for (int j = 0; j < 32; ++j) sum += lcnt[(wv * 32 + j) * 64 + lane];
        wtot[wv * 64 + lane] = sum;
        __syncthreads();

        if (tid < 64) {
            int run = 0;
            #pragma unroll
            for (int w2 = 0; w2 < 4; ++w2) {
                int t = wtot[w2 * 64 + tid];
                wtot[w2 * 64 + tid] = run;
                run += t;
            }
        }
        __syncthreads();

        int run = wtot[wv * 64 + lane];
        for (int j = 0; j < 32; ++j) {
            int c = (wv * 32 + j) * 64 + lane;
            int v = lcnt[c];
            lcnt[c] = run;
            run += v;
        }
        __syncthreads();

        for (int j = 0; j < 32; ++j) {
            int s = j * 256 + tid;
            int e = (int)out[OFF_IDX + s];
            out[OFF_LOC + s] = (float)(lcnt[(s >> 6) * 64 + e] + rk[s]);
        }
    }
}

extern "C" void kernel_launch(void* const* d_in, const int* in_sizes, int n_in,
                              void* d_out, int out_size, void* d_ws, size_t ws_size,
                              hipStream_t stream)
{
    const float* x = (const float*)d_in[0];   // [8192, 4096] fp32
    const float* W = (const float*)d_in[1];   // [64, 4096] fp32
    float* out = (float*)d_out;               // 24578 fp32

    int*   done = (int*)d_ws + WS_DONE_OFF;
    float* Wp   = (float*)d_ws + WS_WP_OFF;
    int*   cnt  = (int*)d_ws + WS_CNT_OFF;
    int*   rk   = (int*)d_ws + WS_RK_OFF;
    float* part = (float*)d_ws + WS_PART_OFF;

    wp_pack<<<256, 256, 0, stream>>>(W, Wp);
    gate_partial<SPLIT><<<dim3(256, SPLIT), 256, 0, stream>>>(x, Wp, part, done);
    reduce_all<SPLIT><<<128, 256, 0, stream>>>(part, out, cnt, rk, done);
}